// Round 3
// baseline (119.494 us; speedup 1.0000x reference)
//
#include <hip/hip_runtime.h>

// Problem constants (fixed by setup_inputs): B=8, C=64, NX=NY=512.
#define BATCH 8
#define CCH   64            // num_bev_features
#define NXC   512
#define NYC   512
#define SLOTS (NXC * NYC)   // 262144 slots per batch image
#define S4    (SLOTS / 4)   // 65536 float4-groups per (b,c) plane

typedef float f32x4 __attribute__((ext_vector_type(4)));

// Pass 0: init winner to -1 (runtime fillBufferAligned ran at 26 GB/s; ours ~1.4us).
__global__ void init_winner(int4* __restrict__ winner4) {
    int i = blockIdx.x * blockDim.x + threadIdx.x;   // exactly BATCH*SLOTS/4 threads
    winner4[i] = make_int4(-1, -1, -1, -1);
}

// Pass 1: last-write-wins winner per flat slot via atomicMax on pillar index.
// max is commutative -> deterministic; "largest i wins" == numpy assignment
// semantics (verified: absmax 0.0).
__global__ void winner_kernel(const int* __restrict__ coords,
                              int* __restrict__ winner, int n) {
    int i = blockIdx.x * blockDim.x + threadIdx.x;
    if (i >= n) return;
    int4 c4 = *reinterpret_cast<const int4*>(coords + (size_t)i * 4);
    int flat = c4.x * SLOTS + c4.y + c4.z * NXC + c4.w;  // b*nx*ny + z + y*nx + x
    atomicMax(&winner[flat], i);
}

// Pass 2: fused zero-fill + gather. One thread owns (batch b, slot-group of 4)
// across ALL 64 channels:
//   - winner int4 read exactly ONCE per slot-group (8.4 MB total, was 8x that)
//   - each non-empty feat row (256 B) read sequentially by one lane -> its
//     2-4 cache lines are fetched once into one CU's L1/L2 (was 8 blocks/XCDs)
//   - per cg: 8 coalesced nontemporal f32x4 plane-stores (1 KB/wave/stream)
// Empty winners skip feat loads and emit zeros.
__global__ void fill_gather3(const float* __restrict__ feat,
                             const int* __restrict__ winner,
                             float* __restrict__ out) {
    int e = blockIdx.x * blockDim.x + threadIdx.x;  // BATCH * S4 threads
    int p4 = e & (S4 - 1);          // slot-group within plane
    int b  = e >> 16;               // batch

    int4 w4 = *reinterpret_cast<const int4*>(winner + (size_t)b * SLOTS + (size_t)p4 * 4);
    int w[4] = {w4.x, w4.y, w4.z, w4.w};
    const float* row[4];
    #pragma unroll
    for (int j = 0; j < 4; ++j)
        row[j] = (w[j] >= 0) ? (feat + (size_t)w[j] * CCH) : nullptr;

    size_t obase = (size_t)b * CCH * SLOTS + (size_t)p4 * 4;

    #pragma unroll 2
    for (int cg = 0; cg < 8; ++cg) {
        const int c0 = cg * 8;
        float f[4][8];
        #pragma unroll
        for (int j = 0; j < 4; ++j) {
            if (row[j]) {
                float4 lo = *reinterpret_cast<const float4*>(row[j] + c0);
                float4 hi = *reinterpret_cast<const float4*>(row[j] + c0 + 4);
                f[j][0] = lo.x; f[j][1] = lo.y; f[j][2] = lo.z; f[j][3] = lo.w;
                f[j][4] = hi.x; f[j][5] = hi.y; f[j][6] = hi.z; f[j][7] = hi.w;
            } else {
                #pragma unroll
                for (int c = 0; c < 8; ++c) f[j][c] = 0.0f;
            }
        }
        #pragma unroll
        for (int c = 0; c < 8; ++c) {
            f32x4 v = {f[0][c], f[1][c], f[2][c], f[3][c]};
            __builtin_nontemporal_store(v,
                reinterpret_cast<f32x4*>(out + obase + (size_t)(c0 + c) * SLOTS));
        }
    }
}

extern "C" void kernel_launch(void* const* d_in, const int* in_sizes, int n_in,
                              void* d_out, int out_size, void* d_ws, size_t ws_size,
                              hipStream_t stream) {
    const float* feat   = (const float*)d_in[0];   // (N, 64) f32
    const int*   coords = (const int*)d_in[1];     // (N, 4)  i32
    float*       out    = (float*)d_out;           // (8, 64, 512, 512) f32
    int n = in_sizes[1] / 4;                       // N = 200000

    int* winner = (int*)d_ws;                      // 8 MiB: BATCH*SLOTS ints

    init_winner<<<(BATCH * SLOTS / 4) / 256, 256, 0, stream>>>((int4*)winner);
    winner_kernel<<<(n + 255) / 256, 256, 0, stream>>>(coords, winner, n);

    int total_threads = BATCH * S4;                // 524,288 threads, 2048 blocks
    fill_gather3<<<total_threads / 256, 256, 0, stream>>>(feat, winner, out);
}